// Round 8
// baseline (52.157 us; speedup 1.0000x reference)
//
#include <hip/hip_runtime.h>
#include <hip/hip_bf16.h>

// ARD kernel matrix: out[i][j] = exp(-0.5 * sum_d (x[i][d]-y[j][d])^2 / exp(lbw[d]))
// Quadratic expansion: weight rows by exp(-0.5*lbw), cast bf16, MFMA GEMM for
// the cross term, fused epilogue exp(-0.5*(x2+y2-2*cross)).
//
// Round 8: ROW-BAND STREAMING, NO LDS, NO BARRIERS. All prior rounds wrote
// strided tiles (<=2KB segments @16KB stride -> ~4-16 of ~128 HBM channel
// units per block, 1.57 TB/s measured) with barrier'd LDS loops. New: block =
// 32 rows x 512 cols; the 8 concurrent col-eighth blocks of a band complete
// full linear 16KB rows. K=256 fits in registers: A frags resident (64 VGPR),
// B frags double-buffered from global (L2-resident per XCD), epilogue+store
// per col-frag so the write stream flows for the kernel's whole duration.

typedef __attribute__((ext_vector_type(8))) short bf16x8;   // 8 bf16 = 4 VGPRs
typedef __attribute__((ext_vector_type(4))) float f32x4;    // MFMA accumulator

#define NN 4096
#define MM 4096
#define DD 256

#define MFMA_BF16 __builtin_amdgcn_mfma_f32_16x16x32_bf16

// ---------------------------------------------------------------------------
// prep: one wave per row (x rows then y rows). Scale by exp(-0.5*lbw), cast
// bf16, accumulate row norm from the ROUNDED values (keeps pdist >= 0).
// ---------------------------------------------------------------------------
__global__ __launch_bounds__(256) void ard_prep(
    const float* __restrict__ x, const float* __restrict__ y,
    const float* __restrict__ lbw,
    __hip_bfloat16* __restrict__ xw, __hip_bfloat16* __restrict__ yw,
    float* __restrict__ x2, float* __restrict__ y2)
{
    const int lane = threadIdx.x & 63;
    const int row  = blockIdx.x * 4 + (threadIdx.x >> 6);   // 0 .. N+M-1

    const float* src;
    __hip_bfloat16* dst;
    float* nrm;
    if (row < NN) {
        src = x + (size_t)row * DD;
        dst = xw + (size_t)row * DD;
        nrm = x2 + row;
    } else {
        const int r = row - NN;
        src = y + (size_t)r * DD;
        dst = yw + (size_t)r * DD;
        nrm = y2 + r;
    }

    const float4 v  = reinterpret_cast<const float4*>(src)[lane];
    const float4 lw = reinterpret_cast<const float4*>(lbw)[lane];

    float wv[4];
    wv[0] = v.x * __expf(-0.5f * lw.x);
    wv[1] = v.y * __expf(-0.5f * lw.y);
    wv[2] = v.z * __expf(-0.5f * lw.z);
    wv[3] = v.w * __expf(-0.5f * lw.w);

    __hip_bfloat16 h[4];
    float s = 0.0f;
#pragma unroll
    for (int j = 0; j < 4; ++j) {
        h[j] = __float2bfloat16(wv[j]);
        const float f = __bfloat162float(h[j]);
        s += f * f;
    }

    reinterpret_cast<uint2*>(dst)[lane] = *reinterpret_cast<uint2*>(h);

#pragma unroll
    for (int off = 32; off > 0; off >>= 1) s += __shfl_down(s, off);
    if (lane == 0) *nrm = s;
}

// ---------------------------------------------------------------------------
// Streaming GEMM. Block = 32 rows x 512 cols, 4 waves (wave = 32 x 128).
// Frags of mfma_f32_16x16x32_bf16 with OPERANDS SWAPPED (y-frag in slot A):
//   D "col" (lane&15)          -> output ROW (xw row)
//   D "row" ((lane>>4)*4+reg)  -> output COL (yw row), 4 consecutive.
// A/B fragment global addressing (verified R4-R7, sans swizzle): lane reads
// 16B at (row_base + lane&15)*512B + kt*64 + (lane>>4)*16.
// ---------------------------------------------------------------------------
__global__ __launch_bounds__(256) void ard_gemm(
    const __hip_bfloat16* __restrict__ A,   // xw [N][D]
    const __hip_bfloat16* __restrict__ B,   // yw [M][D]
    const float* __restrict__ x2, const float* __restrict__ y2,
    float* __restrict__ out)                // [N][M]
{
    const int tid  = threadIdx.x;
    const int lane = tid & 63;
    const int wid  = tid >> 6;        // 0..3

    // band = bid>>3 (32-row band), col-eighth = bid&7 (fast index: the 8
    // concurrent blocks of a band complete full output rows; XCD x keeps
    // col-eighth x -> 256 KB B working set, L2-resident).
    const int bid   = blockIdx.x;
    const int band  = bid >> 3;       // 0..127
    const int q     = bid & 7;        // 0..7
    const int row0  = band * 32;
    const int wcol0 = q * 512 + wid * 128;   // this wave's 128-col strip

    const int cl = lane & 15;
    const int g  = lane >> 4;         // 0..3

    // ---- resident A fragments: 2 m-frags x 8 k-steps (64 VGPR) ----------
    bf16x8 afr[2][8];
#pragma unroll
    for (int m = 0; m < 2; ++m) {
        const char* ap = (const char*)(A + (size_t)(row0 + m * 16 + cl) * DD) + g * 16;
#pragma unroll
        for (int kt = 0; kt < 8; ++kt)
            afr[m][kt] = *reinterpret_cast<const bf16x8*>(ap + kt * 64);
    }

    const float xv0 = x2[row0 + cl];
    const float xv1 = x2[row0 + 16 + cl];
    float* const orow0 = out + (size_t)(row0 + cl) * MM;
    float* const orow1 = out + (size_t)(row0 + 16 + cl) * MM;

    auto loadB = [&](bf16x8* bf, int cf) {
        const char* bp = (const char*)(B + (size_t)(wcol0 + cf * 16 + cl) * DD) + g * 16;
#pragma unroll
        for (int kt = 0; kt < 8; ++kt)
            bf[kt] = *reinterpret_cast<const bf16x8*>(bp + kt * 64);
    };

    auto compute = [&](const bf16x8* bf, int cf) {
        // 4 independent MFMA chains (2 per m-frag) to hide accum latency
        f32x4 p0 = {}, p1 = {}, p2 = {}, p3 = {};
#pragma unroll
        for (int kt = 0; kt < 8; kt += 2) {
            p0 = MFMA_BF16(bf[kt],     afr[0][kt],     p0, 0, 0, 0);
            p1 = MFMA_BF16(bf[kt + 1], afr[0][kt + 1], p1, 0, 0, 0);
            p2 = MFMA_BF16(bf[kt],     afr[1][kt],     p2, 0, 0, 0);
            p3 = MFMA_BF16(bf[kt + 1], afr[1][kt + 1], p3, 0, 0, 0);
        }
        const f32x4 acc0 = p0 + p1;
        const f32x4 acc1 = p2 + p3;

        const int c = wcol0 + cf * 16 + g * 4;
        const float4 yv = *reinterpret_cast<const float4*>(y2 + c);
        f32x4 o;
        o.x = __expf(-0.5f * fmaxf(xv0 + yv.x - 2.0f * acc0[0], 0.0f));
        o.y = __expf(-0.5f * fmaxf(xv0 + yv.y - 2.0f * acc0[1], 0.0f));
        o.z = __expf(-0.5f * fmaxf(xv0 + yv.z - 2.0f * acc0[2], 0.0f));
        o.w = __expf(-0.5f * fmaxf(xv0 + yv.w - 2.0f * acc0[3], 0.0f));
        *reinterpret_cast<f32x4*>(orow0 + c) = o;
        o.x = __expf(-0.5f * fmaxf(xv1 + yv.x - 2.0f * acc1[0], 0.0f));
        o.y = __expf(-0.5f * fmaxf(xv1 + yv.y - 2.0f * acc1[1], 0.0f));
        o.z = __expf(-0.5f * fmaxf(xv1 + yv.z - 2.0f * acc1[2], 0.0f));
        o.w = __expf(-0.5f * fmaxf(xv1 + yv.w - 2.0f * acc1[3], 0.0f));
        *reinterpret_cast<f32x4*>(orow1 + c) = o;
    };

    // 8 col-frags per wave, software-pipelined with two named B buffers
    bf16x8 bb0[8], bb1[8];
    loadB(bb0, 0);
#pragma unroll
    for (int p = 0; p < 4; ++p) {
        loadB(bb1, 2 * p + 1);
        compute(bb0, 2 * p);
        if (p < 3) loadB(bb0, 2 * p + 2);
        compute(bb1, 2 * p + 1);
    }
}

extern "C" void kernel_launch(void* const* d_in, const int* in_sizes, int n_in,
                              void* d_out, int out_size, void* d_ws, size_t ws_size,
                              hipStream_t stream) {
    const float* x   = (const float*)d_in[0];
    const float* y   = (const float*)d_in[1];
    const float* lbw = (const float*)d_in[2];
    float* out = (float*)d_out;

    char* ws = (char*)d_ws;
    __hip_bfloat16* xw = (__hip_bfloat16*)ws;                             // 2 MB
    __hip_bfloat16* yw = (__hip_bfloat16*)(ws + (size_t)2 * 1024 * 1024); // 2 MB
    float* x2 = (float*)(ws + (size_t)4 * 1024 * 1024);                   // 16 KB
    float* y2 = (float*)(ws + (size_t)4 * 1024 * 1024 + 16384);           // 16 KB

    ard_prep<<<(NN + MM) / 4, 256, 0, stream>>>(x, y, lbw, xw, yw, x2, y2);

    // 1024 blocks = 128 row-bands x 8 col-eighths (eighth fastest)
    ard_gemm<<<1024, 256, 0, stream>>>(xw, yw, x2, y2, out);
}